// Round 6
// baseline (199.897 us; speedup 1.0000x reference)
//
#include <hip/hip_runtime.h>

typedef __attribute__((ext_vector_type(4))) float f32x4;
typedef __attribute__((ext_vector_type(8))) short s16x8;

#define NSKIN 128
#define NG    8000
#define NRPT  8000
#define MT    128
#define NT    128
#define KK    32
#define KCH   1000
#define NKC   8
#define NRB   64
#define TPB   512

#define TILE_B  8192          // one 128x32 bf16 tile, 64B rows
#define BUF_B   (4*TILE_B)    // Ar|Ai|Bc|Bs
#define OFF_AR  0
#define OFF_AI  8192
#define OFF_BC  16384
#define OFF_BS  24576

__device__ __forceinline__ float sin_rev(float u){ float r; asm("v_sin_f32 %0, %1" : "=v"(r) : "v"(u)); return r; }
__device__ __forceinline__ float cos_rev(float u){ float r; asm("v_cos_f32 %0, %1" : "=v"(r) : "v"(u)); return r; }
__device__ __forceinline__ unsigned int cvt_pk(float lo, float hi){
    unsigned int r; asm("v_cvt_pk_bf16_f32 %0, %1, %2" : "=v"(r) : "v"(lo), "v"(hi)); return r;
}
__device__ __forceinline__ s16x8 bneg(s16x8 v){
    int4 u = *(int4*)&v;
    u.x ^= 0x80008000; u.y ^= 0x80008000; u.z ^= 0x80008000; u.w ^= 0x80008000;
    return *(s16x8*)&u;
}
// byte offset of 16B granule (row,kg) in swizzled [128][32]-ushort tile (64B rows).
// kg' = kg ^ ((row>>1)&3): b128 writes (sa=tid>>2,seg=tid&3) and b128 frag reads
// (rows base+frow, kg=lane>>4) both land 8 lanes per 16B bank-group -> conflict-free.
// xor term depends only on row bits [2:1] -> invariant under row+16 -> +1024B strides.
__device__ __forceinline__ int swz(int row, int kg){
    return row*64 + ((kg ^ ((row>>1)&3))<<4);
}

__global__ __launch_bounds__(TPB, 4) void bloch_mfma5(
    const float* __restrict__ Amat, const float* __restrict__ kgrid,
    const float* __restrict__ cgr,  const float* __restrict__ cgi,
    const float* __restrict__ rpts, float* __restrict__ out, int out_size)
{
    __shared__ __align__(16) char tiles[2*BUF_B];   // 64 KB double buffer
    __shared__ float fracS[NT][4];
    __shared__ float rkS[NT][4];
    __shared__ float2 ekrS[NT][4];
    __shared__ float invAS[9];
    __shared__ float scaleS;

    const int tid = threadIdx.x;
    const int bid = blockIdx.x;
    // kc = bid>>6: the 8 kc-partners of an output tile share bid%8 -> same XCD
    // -> epilogue atomic lines stay in one L2.
    const int kc  = bid >> 6;
    const int rb  = bid & 63;
    const int r_base  = rb * NT;
    const int k_begin = kc * KCH;
    const int k_end   = k_begin + KCH;

    if (tid == 0) {
        float a00=Amat[0],a01=Amat[1],a02=Amat[2];
        float a10=Amat[3],a11=Amat[4],a12=Amat[5];
        float a20=Amat[6],a21=Amat[7],a22=Amat[8];
        float c00 =  (a11*a22 - a12*a21);
        float c01 = -(a10*a22 - a12*a20);
        float c02 =  (a10*a21 - a11*a20);
        float det = a00*c00 + a01*c01 + a02*c02;
        float id  = 1.0f/det;
        invAS[0] =  c00*id;
        invAS[1] = -(a01*a22 - a02*a21)*id;
        invAS[2] =  (a01*a12 - a02*a11)*id;
        invAS[3] =  c01*id;
        invAS[4] =  (a00*a22 - a02*a20)*id;
        invAS[5] = -(a00*a12 - a02*a10)*id;
        invAS[6] =  c02*id;
        invAS[7] = -(a00*a21 - a01*a20)*id;
        invAS[8] =  (a00*a11 - a01*a10)*id;
        scaleS   = rsqrtf(fabsf(det));
    }
    __syncthreads();

    if (tid < NT) {
        int rg = r_base + tid; if (rg > NRPT-1) rg = NRPT-1;
        float r0 = rpts[rg*3+0], r1 = rpts[rg*3+1], r2 = rpts[rg*3+2];
        fracS[tid][0] = r0*invAS[0] + r1*invAS[3] + r2*invAS[6];
        fracS[tid][1] = r0*invAS[1] + r1*invAS[4] + r2*invAS[7];
        fracS[tid][2] = r0*invAS[2] + r1*invAS[5] + r2*invAS[8];
        #pragma unroll
        for (int kk = 0; kk < 4; ++kk)
            rkS[tid][kk] = r0*kgrid[kk*3+0] + r1*kgrid[kk*3+1] + r2*kgrid[kk*3+2];
    }
    __syncthreads();

    f32x4 accRe[4][2], accIm[4][2];
    #pragma unroll
    for (int mi = 0; mi < 4; ++mi)
        #pragma unroll
        for (int ni = 0; ni < 2; ++ni) {
            accRe[mi][ni] = (f32x4){0.f,0.f,0.f,0.f};
            accIm[mi][ni] = (f32x4){0.f,0.f,0.f,0.f};
        }

    const int lane = tid & 63;
    const int wid  = tid >> 6;
    const int wm   = wid >> 2;      // 0..1  (M half)
    const int wn   = wid & 3;       // 0..3  (N quarter)
    const int frow = lane & 15;
    const int kq   = lane >> 4;     // 16B granule 0..3

    const int sa      = tid >> 2;   // stage row 0..127
    const int seg     = tid & 3;    // k granule 0..3

    // loop-invariant byte offsets
    const int stOff = swz(sa, seg);
    const int aOff  = swz(wm*64 + frow, kq);
    const int bOff  = swz(wn*32 + frow, kq);

    const float f0r = fracS[sa][0], f1r = fracS[sa][1], f2r = fracS[sa][2];

    // recurrence constants: w1 = e^{2pi i f2}, w1wd = w1*e^{-2pi i 20 f2}
    float u1 = f2r - floorf(f2r);
    const float w1c = cos_rev(u1), w1s = sin_rev(u1);
    float yd = -20.0f * f2r; yd -= floorf(yd);
    const float wdc = cos_rev(yd), wds = sin_rev(yd);
    const float w1wdc = w1c*wdc - w1s*wds;
    const float w1wds = w1c*wds + w1s*wdc;

    float4 pvr0, pvr1, pvi0, pvi1;   // prefetched A (fp32)

    auto loadA = [&](int kb){
        int kg = kb + seg*8;
        if (kb < k_end && kg < k_end) {
            const float* pr_ = &cgr[(size_t)sa*NG + kg];
            const float* pi_ = &cgi[(size_t)sa*NG + kg];
            pvr0 = *(const float4*)pr_;  pvr1 = *(const float4*)(pr_+4);
            pvi0 = *(const float4*)pi_;  pvi1 = *(const float4*)(pi_+4);
        } else {
            pvr0 = make_float4(0.f,0.f,0.f,0.f); pvr1 = pvr0;
            pvi0 = pvr0; pvi1 = pvr0;
        }
    };
    auto stageA = [&](char* wb){
        uint4 pr, pi;
        pr.x = cvt_pk(pvr0.x, pvr0.y); pr.y = cvt_pk(pvr0.z, pvr0.w);
        pr.z = cvt_pk(pvr1.x, pvr1.y); pr.w = cvt_pk(pvr1.z, pvr1.w);
        pi.x = cvt_pk(pvi0.x, pvi0.y); pi.y = cvt_pk(pvi0.z, pvi0.w);
        pi.z = cvt_pk(pvi1.x, pvi1.y); pi.w = cvt_pk(pvi1.z, pvi1.w);
        *(uint4*)(wb + OFF_AR + stOff) = pr;
        *(uint4*)(wb + OFF_AI + stOff) = pi;
    };
    auto stageB = [&](int kb, char* wb){
        int g0   = kb + seg*8;
        int i12  = (g0 * 3277) >> 16;            // g0/20 (exact, g0<16000)
        int i3_0 = g0 - i12*20;
        int i1a  = (i12 * 3277) >> 16; int i2a = i12 - i1a*20;
        int i12b = i12 + 1;
        int i1b  = (i12b * 3277) >> 16; int i2b = i12b - i1b*20;
        float m1a = (float)(i1a - (i1a >= 10 ? 20 : 0));
        float m2a = (float)(i2a - (i2a >= 10 ? 20 : 0));
        float m1b = (float)(i1b - (i1b >= 10 ? 20 : 0));
        float m2b = (float)(i2b - (i2b >= 10 ? 20 : 0));
        float m30 = (float)(i3_0 - (i3_0 >= 10 ? 20 : 0));
        float y0 = m1a*f0r + m2a*f1r + m30*f2r; y0 -= floorf(y0);
        float cc = cos_rev(y0), cs = sin_rev(y0);
        float rd = (m1b-m1a)*f0r + (m2b-m2a)*f1r; rd -= floorf(rd);
        float rc = cos_rev(rd), rs = sin_rev(rd);
        float wXc = w1c*rc - w1s*rs;
        float wXs = w1c*rs + w1s*rc;
        float bcv[8], bsv[8];
        bcv[0] = cc; bsv[0] = cs;
        #pragma unroll
        for (int j = 1; j < 8; ++j) {
            bool cB = (i3_0 == 20 - j);   // i12 boundary
            bool cD = (i3_0 == 10 - j);   // m3 decade jump
            float mc = cB ? wXc : (cD ? w1wdc : w1c);
            float ms = cB ? wXs : (cD ? w1wds : w1s);
            float nc = cc*mc - cs*ms;
            float ns = cc*ms + cs*mc;
            cc = nc; cs = ns;
            bcv[j] = cc; bsv[j] = cs;
        }
        uint4 wc, wsn;
        wc.x  = cvt_pk(bcv[0], bcv[1]); wc.y  = cvt_pk(bcv[2], bcv[3]);
        wc.z  = cvt_pk(bcv[4], bcv[5]); wc.w  = cvt_pk(bcv[6], bcv[7]);
        wsn.x = cvt_pk(bsv[0], bsv[1]); wsn.y = cvt_pk(bsv[2], bsv[3]);
        wsn.z = cvt_pk(bsv[4], bsv[5]); wsn.w = cvt_pk(bsv[6], bsv[7]);
        *(uint4*)(wb + OFF_BC + stOff) = wc;
        *(uint4*)(wb + OFF_BS + stOff) = wsn;
    };

    // prologue: stage tile0 into buf0, prefetch tile1
    loadA(k_begin);
    stageA(tiles);
    stageB(k_begin, tiles);
    loadA(k_begin + KK);
    __syncthreads();

    int p = 0;
    #pragma unroll 1
    for (int kb = k_begin; kb < k_end; kb += KK) {
        const char* rb_ = tiles + p*BUF_B;
        char*       wb_ = tiles + (p^1)*BUF_B;
        const bool hn = (kb + KK < k_end);

        // issue fragment reads from buf p early
        s16x8 bcf[2], bsf[2], bsnf[2];
        #pragma unroll
        for (int ni = 0; ni < 2; ++ni) {
            bcf[ni]  = *(const s16x8*)(rb_ + OFF_BC + bOff + ni*1024);
            bsf[ni]  = *(const s16x8*)(rb_ + OFF_BS + bOff + ni*1024);
            bsnf[ni] = bneg(bsf[ni]);
        }
        s16x8 arf[4], aif[4];
        #pragma unroll
        for (int mi = 0; mi < 4; ++mi) {
            arf[mi] = *(const s16x8*)(rb_ + OFF_AR + aOff + mi*1024);
            aif[mi] = *(const s16x8*)(rb_ + OFF_AI + aOff + mi*1024);
        }

        // stage tile t+1 into buf q (VALU; overlaps MFMAs below)
        if (hn) {
            stageA(wb_);
            stageB(kb + KK, wb_);
            loadA(kb + 2*KK);
        }

        // MFMAs (compiler interleaves with staging VALU)
        #pragma unroll
        for (int mi = 0; mi < 4; ++mi)
            #pragma unroll
            for (int ni = 0; ni < 2; ++ni) {
                // Re += Ar*c + Ai*(-s) ; Im += Ar*s + Ai*c
                accRe[mi][ni] = __builtin_amdgcn_mfma_f32_16x16x32_bf16(arf[mi], bcf[ni],  accRe[mi][ni], 0, 0, 0);
                accRe[mi][ni] = __builtin_amdgcn_mfma_f32_16x16x32_bf16(aif[mi], bsnf[ni], accRe[mi][ni], 0, 0, 0);
                accIm[mi][ni] = __builtin_amdgcn_mfma_f32_16x16x32_bf16(arf[mi], bsf[ni],  accIm[mi][ni], 0, 0, 0);
                accIm[mi][ni] = __builtin_amdgcn_mfma_f32_16x16x32_bf16(aif[mi], bcf[ni],  accIm[mi][ni], 0, 0, 0);
            }

        __syncthreads();
        p ^= 1;
    }

    // ---- e^{i k.r} table: one sincos per thread ----
    {
        int col = tid >> 2, kidx = tid & 3;
        const float inv2pi = 0.15915494309189535f;
        float ang = rkS[col][kidx] * inv2pi;
        float u = ang - floorf(ang);
        ekrS[col][kidx] = make_float2(cos_rev(u), sin_rev(u));
    }
    __syncthreads();

    // ---- epilogue: rotate by exp(i k.r), scale, atomic-accumulate ----
    const bool write_imag = (out_size >= 2*NSKIN*NRPT);
    const float scale = scaleS;
    #pragma unroll
    for (int mi = 0; mi < 4; ++mi) {
        const int m0 = wm*64 + mi*16;
        const int kidx = (m0 >> 4) & 3;
        #pragma unroll
        for (int ni = 0; ni < 2; ++ni) {
            int col = wn*32 + ni*16 + frow;
            int rg = r_base + col;
            if (rg < NRPT) {
                float2 ekr = ekrS[col][kidx];
                float ck = ekr.x, sk = ekr.y;
                #pragma unroll
                for (int v = 0; v < 4; ++v) {
                    int sg = m0 + kq*4 + v;
                    float re = accRe[mi][ni][v];
                    float im = accIm[mi][ni][v];
                    float orr = (re*ck - im*sk) * scale;
                    size_t lin = (size_t)sg * NRPT + rg;
                    if (write_imag) {
                        float oi = (re*sk + im*ck) * scale;
                        size_t idx = lin * 2;
                        if (idx + 1 < (size_t)out_size) {
                            atomicAdd(&out[idx],   orr);
                            atomicAdd(&out[idx+1], oi);
                        }
                    } else {
                        if (lin < (size_t)out_size)
                            atomicAdd(&out[lin], orr);
                    }
                }
            }
        }
    }
}

extern "C" void kernel_launch(void* const* d_in, const int* in_sizes, int n_in,
                              void* d_out, int out_size, void* d_ws, size_t ws_size,
                              hipStream_t stream) {
    const float* Amat  = (const float*)d_in[0];
    const float* kgrid = (const float*)d_in[1];
    const float* cgr   = (const float*)d_in[2];
    const float* cgi   = (const float*)d_in[3];
    const float* rpts  = (const float*)d_in[4];
    float* out = (float*)d_out;

    hipMemsetAsync(d_out, 0, (size_t)out_size * sizeof(float), stream);

    dim3 grid(NRB * NKC);   // 64 rb x 8 kc = 512 blocks (2/CU)
    bloch_mfma5<<<grid, TPB, 0, stream>>>(Amat, kgrid, cgr, cgi, rpts, out, out_size);
}

// Round 7
// 94.441 us; speedup vs baseline: 2.1166x; 2.1166x over previous
//
#include <hip/hip_runtime.h>

typedef __attribute__((ext_vector_type(4))) float f32x4;
typedef __attribute__((ext_vector_type(8))) short s16x8;

#define NSKIN 128
#define NG    8000
#define NRPT  8000
#define MT    128
#define NT    128
#define KK    32
#define KCH   1000
#define NKC   8
#define NRB   64
#define TPB   512

#define TILE_B  8192          // one 128x32 bf16 tile, 64B rows
#define BUF_B   (4*TILE_B)    // Ar|Ai|Bc|Bs
#define OFF_AR  0
#define OFF_AI  8192
#define OFF_BC  16384
#define OFF_BS  24576

__device__ __forceinline__ float sin_rev(float u){ float r; asm("v_sin_f32 %0, %1" : "=v"(r) : "v"(u)); return r; }
__device__ __forceinline__ float cos_rev(float u){ float r; asm("v_cos_f32 %0, %1" : "=v"(r) : "v"(u)); return r; }
__device__ __forceinline__ unsigned int cvt_pk(float lo, float hi){
    unsigned int r; asm("v_cvt_pk_bf16_f32 %0, %1, %2" : "=v"(r) : "v"(lo), "v"(hi)); return r;
}
__device__ __forceinline__ s16x8 bneg(s16x8 v){
    int4 u = *(int4*)&v;
    u.x ^= 0x80008000; u.y ^= 0x80008000; u.z ^= 0x80008000; u.w ^= 0x80008000;
    return *(s16x8*)&u;
}
// byte offset of 16B granule (row,kg) in swizzled [128][32]-ushort tile (64B rows).
// kg' = kg ^ ((row>>1)&3): b128 stage-writes (sa=tid>>2,seg=tid&3) and b128 frag
// reads (rows base+frow, kg=lane>>4) both land 8 lanes per 16B bank-group.
// xor term depends only on row bits [2:1] -> invariant under row+16 -> +1024B strides.
__device__ __forceinline__ int swz(int row, int kg){
    return row*64 + ((kg ^ ((row>>1)&3))<<4);
}

__global__ __launch_bounds__(TPB, 4) void bloch_mfma6(
    const float* __restrict__ Amat, const float* __restrict__ kgrid,
    const float* __restrict__ cgr,  const float* __restrict__ cgi,
    const float* __restrict__ rpts, float* __restrict__ out, int out_size)
{
    __shared__ __align__(16) char tiles[2*BUF_B];   // 64 KB double buffer
    __shared__ float fracS[NT][4];
    __shared__ float rkS[NT][4];
    __shared__ float2 ekrS[NT][4];
    __shared__ float invAS[9];
    __shared__ float scaleS;

    const int tid = threadIdx.x;
    const int bid = blockIdx.x;
    // kc = bid>>6: the 8 kc-partners of an output tile share bid%8 -> same XCD
    // -> epilogue atomic lines stay in one L2.
    const int kc  = bid >> 6;
    const int rb  = bid & 63;
    const int r_base  = rb * NT;
    const int k_begin = kc * KCH;
    const int k_end   = k_begin + KCH;

    if (tid == 0) {
        float a00=Amat[0],a01=Amat[1],a02=Amat[2];
        float a10=Amat[3],a11=Amat[4],a12=Amat[5];
        float a20=Amat[6],a21=Amat[7],a22=Amat[8];
        float c00 =  (a11*a22 - a12*a21);
        float c01 = -(a10*a22 - a12*a20);
        float c02 =  (a10*a21 - a11*a20);
        float det = a00*c00 + a01*c01 + a02*c02;
        float id  = 1.0f/det;
        invAS[0] =  c00*id;
        invAS[1] = -(a01*a22 - a02*a21)*id;
        invAS[2] =  (a01*a12 - a02*a11)*id;
        invAS[3] =  c01*id;
        invAS[4] =  (a00*a22 - a02*a20)*id;
        invAS[5] = -(a00*a12 - a02*a10)*id;
        invAS[6] =  c02*id;
        invAS[7] = -(a00*a21 - a01*a20)*id;
        invAS[8] =  (a00*a11 - a01*a10)*id;
        scaleS   = rsqrtf(fabsf(det));
    }
    __syncthreads();

    if (tid < NT) {
        int rg = r_base + tid; if (rg > NRPT-1) rg = NRPT-1;
        float r0 = rpts[rg*3+0], r1 = rpts[rg*3+1], r2 = rpts[rg*3+2];
        fracS[tid][0] = r0*invAS[0] + r1*invAS[3] + r2*invAS[6];
        fracS[tid][1] = r0*invAS[1] + r1*invAS[4] + r2*invAS[7];
        fracS[tid][2] = r0*invAS[2] + r1*invAS[5] + r2*invAS[8];
        #pragma unroll
        for (int kk = 0; kk < 4; ++kk)
            rkS[tid][kk] = r0*kgrid[kk*3+0] + r1*kgrid[kk*3+1] + r2*kgrid[kk*3+2];
    }
    __syncthreads();

    f32x4 accRe[4][2], accIm[4][2];
    #pragma unroll
    for (int mi = 0; mi < 4; ++mi)
        #pragma unroll
        for (int ni = 0; ni < 2; ++ni) {
            accRe[mi][ni] = (f32x4){0.f,0.f,0.f,0.f};
            accIm[mi][ni] = (f32x4){0.f,0.f,0.f,0.f};
        }

    const int lane = tid & 63;
    const int wid  = tid >> 6;
    const int wm   = wid >> 2;      // 0..1  (M half)
    const int wn   = wid & 3;       // 0..3  (N quarter)
    const int frow = lane & 15;
    const int kq   = lane >> 4;     // 16B granule 0..3

    const int sa      = tid >> 2;   // stage row 0..127
    const int seg     = tid & 3;    // k granule 0..3

    // loop-invariant byte offsets
    const int stOff = swz(sa, seg);
    const int aOff  = swz(wm*64 + frow, kq);
    const int bOff  = swz(wn*32 + frow, kq);

    const float f0r = fracS[sa][0], f1r = fracS[sa][1], f2r = fracS[sa][2];

    // recurrence constants: w1 = e^{2pi i f2}, w1wd = w1*e^{-2pi i 20 f2}
    float u1 = f2r - floorf(f2r);
    const float w1c = cos_rev(u1), w1s = sin_rev(u1);
    float yd = -20.0f * f2r; yd -= floorf(yd);
    const float wdc = cos_rev(yd), wds = sin_rev(yd);
    const float w1wdc = w1c*wdc - w1s*wds;
    const float w1wds = w1c*wds + w1s*wdc;

    float4 pvr0, pvr1, pvi0, pvi1;   // prefetched A (fp32)

    auto loadA = [&](int kb){
        int kg = kb + seg*8;
        if (kb < k_end && kg < k_end) {
            const float* pr_ = &cgr[(size_t)sa*NG + kg];
            const float* pi_ = &cgi[(size_t)sa*NG + kg];
            pvr0 = *(const float4*)pr_;  pvr1 = *(const float4*)(pr_+4);
            pvi0 = *(const float4*)pi_;  pvi1 = *(const float4*)(pi_+4);
        } else {
            pvr0 = make_float4(0.f,0.f,0.f,0.f); pvr1 = pvr0;
            pvi0 = pvr0; pvi1 = pvr0;
        }
    };
    auto stageA = [&](char* wb){
        uint4 pr, pi;
        pr.x = cvt_pk(pvr0.x, pvr0.y); pr.y = cvt_pk(pvr0.z, pvr0.w);
        pr.z = cvt_pk(pvr1.x, pvr1.y); pr.w = cvt_pk(pvr1.z, pvr1.w);
        pi.x = cvt_pk(pvi0.x, pvi0.y); pi.y = cvt_pk(pvi0.z, pvi0.w);
        pi.z = cvt_pk(pvi1.x, pvi1.y); pi.w = cvt_pk(pvi1.z, pvi1.w);
        *(uint4*)(wb + OFF_AR + stOff) = pr;
        *(uint4*)(wb + OFF_AI + stOff) = pi;
    };
    auto stageB = [&](int kb, char* wb){
        int g0   = kb + seg*8;
        int i12  = (g0 * 3277) >> 16;            // g0/20 (exact, g0<16000)
        int i3_0 = g0 - i12*20;
        int i1a  = (i12 * 3277) >> 16; int i2a = i12 - i1a*20;
        int i12b = i12 + 1;
        int i1b  = (i12b * 3277) >> 16; int i2b = i12b - i1b*20;
        float m1a = (float)(i1a - (i1a >= 10 ? 20 : 0));
        float m2a = (float)(i2a - (i2a >= 10 ? 20 : 0));
        float m1b = (float)(i1b - (i1b >= 10 ? 20 : 0));
        float m2b = (float)(i2b - (i2b >= 10 ? 20 : 0));
        float m30 = (float)(i3_0 - (i3_0 >= 10 ? 20 : 0));
        float y0 = m1a*f0r + m2a*f1r + m30*f2r; y0 -= floorf(y0);
        float cc = cos_rev(y0), cs = sin_rev(y0);
        float rd = (m1b-m1a)*f0r + (m2b-m2a)*f1r; rd -= floorf(rd);
        float rc = cos_rev(rd), rs = sin_rev(rd);
        float wXc = w1c*rc - w1s*rs;
        float wXs = w1c*rs + w1s*rc;
        float bcv[8], bsv[8];
        bcv[0] = cc; bsv[0] = cs;
        #pragma unroll
        for (int j = 1; j < 8; ++j) {
            bool cB = (i3_0 == 20 - j);   // i12 boundary
            bool cD = (i3_0 == 10 - j);   // m3 decade jump
            float mc = cB ? wXc : (cD ? w1wdc : w1c);
            float ms = cB ? wXs : (cD ? w1wds : w1s);
            float nc = cc*mc - cs*ms;
            float ns = cc*ms + cs*mc;
            cc = nc; cs = ns;
            bcv[j] = cc; bsv[j] = cs;
        }
        uint4 wc, wsn;
        wc.x  = cvt_pk(bcv[0], bcv[1]); wc.y  = cvt_pk(bcv[2], bcv[3]);
        wc.z  = cvt_pk(bcv[4], bcv[5]); wc.w  = cvt_pk(bcv[6], bcv[7]);
        wsn.x = cvt_pk(bsv[0], bsv[1]); wsn.y = cvt_pk(bsv[2], bsv[3]);
        wsn.z = cvt_pk(bsv[4], bsv[5]); wsn.w = cvt_pk(bsv[6], bsv[7]);
        *(uint4*)(wb + OFF_BC + stOff) = wc;
        *(uint4*)(wb + OFF_BS + stOff) = wsn;
    };

    // prologue: stage tile0 into buf0, prefetch tile1
    loadA(k_begin);
    stageA(tiles);
    stageB(k_begin, tiles);
    loadA(k_begin + KK);
    __syncthreads();

    int p = 0;
    #pragma unroll 1
    for (int kb = k_begin; kb < k_end; kb += KK) {
        const char* rb_ = tiles + p*BUF_B;
        char*       wb_ = tiles + (p^1)*BUF_B;
        const bool hn = (kb + KK < k_end);

        // 1) stage tile t+1 into buf q (short live ranges; temps die here)
        if (hn) {
            stageA(wb_);
            stageB(kb + KK, wb_);
            loadA(kb + 2*KK);
        }

        // 2) consume tile t: B frags once, A frags per-mi (keeps live set small)
        s16x8 bcf[2], bsf[2], bsnf[2];
        #pragma unroll
        for (int ni = 0; ni < 2; ++ni) {
            bcf[ni]  = *(const s16x8*)(rb_ + OFF_BC + bOff + ni*1024);
            bsf[ni]  = *(const s16x8*)(rb_ + OFF_BS + bOff + ni*1024);
            bsnf[ni] = bneg(bsf[ni]);
        }
        #pragma unroll
        for (int mi = 0; mi < 4; ++mi) {
            s16x8 arf = *(const s16x8*)(rb_ + OFF_AR + aOff + mi*1024);
            s16x8 aif = *(const s16x8*)(rb_ + OFF_AI + aOff + mi*1024);
            #pragma unroll
            for (int ni = 0; ni < 2; ++ni) {
                // Re += Ar*c + Ai*(-s) ; Im += Ar*s + Ai*c
                accRe[mi][ni] = __builtin_amdgcn_mfma_f32_16x16x32_bf16(arf, bcf[ni],  accRe[mi][ni], 0, 0, 0);
                accRe[mi][ni] = __builtin_amdgcn_mfma_f32_16x16x32_bf16(aif, bsnf[ni], accRe[mi][ni], 0, 0, 0);
                accIm[mi][ni] = __builtin_amdgcn_mfma_f32_16x16x32_bf16(arf, bsf[ni],  accIm[mi][ni], 0, 0, 0);
                accIm[mi][ni] = __builtin_amdgcn_mfma_f32_16x16x32_bf16(aif, bcf[ni],  accIm[mi][ni], 0, 0, 0);
            }
        }

        __syncthreads();
        p ^= 1;
    }

    // ---- e^{i k.r} table: one sincos per thread ----
    {
        int col = tid >> 2, kidx = tid & 3;
        const float inv2pi = 0.15915494309189535f;
        float ang = rkS[col][kidx] * inv2pi;
        float u = ang - floorf(ang);
        ekrS[col][kidx] = make_float2(cos_rev(u), sin_rev(u));
    }
    __syncthreads();

    // ---- epilogue: rotate by exp(i k.r), scale, atomic-accumulate ----
    const bool write_imag = (out_size >= 2*NSKIN*NRPT);
    const float scale = scaleS;
    #pragma unroll
    for (int mi = 0; mi < 4; ++mi) {
        const int m0 = wm*64 + mi*16;
        const int kidx = (m0 >> 4) & 3;
        #pragma unroll
        for (int ni = 0; ni < 2; ++ni) {
            int col = wn*32 + ni*16 + frow;
            int rg = r_base + col;
            if (rg < NRPT) {
                float2 ekr = ekrS[col][kidx];
                float ck = ekr.x, sk = ekr.y;
                #pragma unroll
                for (int v = 0; v < 4; ++v) {
                    int sg = m0 + kq*4 + v;
                    float re = accRe[mi][ni][v];
                    float im = accIm[mi][ni][v];
                    float orr = (re*ck - im*sk) * scale;
                    size_t lin = (size_t)sg * NRPT + rg;
                    if (write_imag) {
                        float oi = (re*sk + im*ck) * scale;
                        size_t idx = lin * 2;
                        if (idx + 1 < (size_t)out_size) {
                            atomicAdd(&out[idx],   orr);
                            atomicAdd(&out[idx+1], oi);
                        }
                    } else {
                        if (lin < (size_t)out_size)
                            atomicAdd(&out[lin], orr);
                    }
                }
            }
        }
    }
}

extern "C" void kernel_launch(void* const* d_in, const int* in_sizes, int n_in,
                              void* d_out, int out_size, void* d_ws, size_t ws_size,
                              hipStream_t stream) {
    const float* Amat  = (const float*)d_in[0];
    const float* kgrid = (const float*)d_in[1];
    const float* cgr   = (const float*)d_in[2];
    const float* cgi   = (const float*)d_in[3];
    const float* rpts  = (const float*)d_in[4];
    float* out = (float*)d_out;

    hipMemsetAsync(d_out, 0, (size_t)out_size * sizeof(float), stream);

    dim3 grid(NRB * NKC);   // 64 rb x 8 kc = 512 blocks (2/CU)
    bloch_mfma6<<<grid, TPB, 0, stream>>>(Amat, kgrid, cgr, cgi, rpts, out, out_size);
}